// Round 3
// baseline (410.505 us; speedup 1.0000x reference)
//
#include <hip/hip_runtime.h>
#include <hip/hip_bf16.h>
#include <stdint.h>

typedef __bf16 bf16;
typedef __bf16 bf16x4 __attribute__((ext_vector_type(4)));
typedef __bf16 bf16x8 __attribute__((ext_vector_type(8)));
typedef float f32x4 __attribute__((ext_vector_type(4)));

#define D_MODEL 768
#define NUM_HEADS 48
#define HEAD_CH 16
#define INNER 2304
#define BATCH 2
#define SEQLEN 2048
#define M_ROWS (BATCH * SEQLEN)
#define EPSF 1e-6f

// async global->LDS, 16B per lane. LDS dest must be wave-uniform base + lane*16.
__device__ inline void gload_lds16(const void* g, void* l) {
  __builtin_amdgcn_global_load_lds((__attribute__((address_space(1))) void*)(g),
                                   (__attribute__((address_space(3))) void*)(l),
                                   16, 0, 0);
}

// ---------------------------------------------------------------------------
// f32 -> bf16 convert (memory-bound, float4 in / bf16x4 out)
// ---------------------------------------------------------------------------
__global__ __launch_bounds__(256) void cvt_f32_bf16(
    const float* __restrict__ src, bf16* __restrict__ dst, int n4) {
  const int i = blockIdx.x * 256 + threadIdx.x;
  if (i < n4) {
    const float4 v = ((const float4*)src)[i];
    bf16x4 o;
    o[0] = (bf16)v.x; o[1] = (bf16)v.y; o[2] = (bf16)v.z; o[3] = (bf16)v.w;
    ((bf16x4*)dst)[i] = o;
  }
}

// ---------------------------------------------------------------------------
// GEMM: C[m,n] = sum_k A[m,k]*W[n,k] + bias[n] (+ skip[m,n]); A (M,K), W (N,K)
// m97 pattern: 128x128 tile, BK=32, 4 waves each 64x64, global_load_lds x16.
// A, W bf16; bias/skip f32; C is CT (bf16 or float).
// ---------------------------------------------------------------------------
template <int NCOLS, bool ADD_SKIP, typename CT>
__global__ __launch_bounds__(256) void gemm_bt(
    const bf16* __restrict__ A, const bf16* __restrict__ W,
    const float* __restrict__ bias, const float* __restrict__ skip,
    CT* __restrict__ C, int K) {
  __shared__ __align__(16) bf16 As[128 * 32];
  __shared__ __align__(16) bf16 Bs[128 * 32];
  const int t = threadIdx.x;
  const int lane = t & 63, w = t >> 6;
  const int wm = (w >> 1) * 64, wn = (w & 1) * 64;
  const int row16 = lane & 15, quad = lane >> 4;
  const int m0 = blockIdx.x * 128, n0 = blockIdx.y * 128;

  f32x4 zero4 = {0.f, 0.f, 0.f, 0.f};
  f32x4 acc[4][4];
#pragma unroll
  for (int mi = 0; mi < 4; ++mi)
#pragma unroll
    for (int ni = 0; ni < 4; ++ni) acc[mi][ni] = zero4;

  const int arow = t >> 2;        // 0..63
  const int acol = (t & 3) * 8;   // k sub-offset
  const bf16* Ab = A + (size_t)m0 * K;
  const bf16* Wb = W + (size_t)n0 * K;

  for (int kt = 0; kt < K; kt += 32) {
    gload_lds16(Ab + (size_t)arow * K + kt + acol, As + t * 8);
    gload_lds16(Ab + (size_t)(64 + arow) * K + kt + acol, As + 2048 + t * 8);
    gload_lds16(Wb + (size_t)arow * K + kt + acol, Bs + t * 8);
    gload_lds16(Wb + (size_t)(64 + arow) * K + kt + acol, Bs + 2048 + t * 8);
    __syncthreads();

    bf16x8 af[4], wf[4];
#pragma unroll
    for (int mi = 0; mi < 4; ++mi)
      af[mi] = *(const bf16x8*)&As[(wm + mi * 16 + row16) * 32 + quad * 8];
#pragma unroll
    for (int ni = 0; ni < 4; ++ni)
      wf[ni] = *(const bf16x8*)&Bs[(wn + ni * 16 + row16) * 32 + quad * 8];
#pragma unroll
    for (int mi = 0; mi < 4; ++mi)
#pragma unroll
      for (int ni = 0; ni < 4; ++ni)
        acc[mi][ni] = __builtin_amdgcn_mfma_f32_16x16x32_bf16(
            af[mi], wf[ni], acc[mi][ni], 0, 0, 0);
    __syncthreads();
  }

#pragma unroll
  for (int mi = 0; mi < 4; ++mi) {
#pragma unroll
    for (int ni = 0; ni < 4; ++ni) {
      const int col = n0 + wn + ni * 16 + row16;
      const float bv = bias[col];
#pragma unroll
      for (int r = 0; r < 4; ++r) {
        const int row = m0 + wm + mi * 16 + quad * 4 + r;
        float v = acc[mi][ni][r] + bv;
        if (ADD_SKIP) v += skip[(size_t)row * NCOLS + col];
        C[(size_t)row * NCOLS + col] = (CT)v;
      }
    }
  }
}

// ---------------------------------------------------------------------------
// V-only causal width-3 conv: channels 32..47 per head -> V (B,N,HC,L) bf16
// ---------------------------------------------------------------------------
__global__ __launch_bounds__(256) void conv_v(
    const bf16* __restrict__ u, const float* __restrict__ w_sf,
    const float* __restrict__ b_sf, bf16* __restrict__ vv) {
  const int nh = blockIdx.x, b = blockIdx.y, lc = blockIdx.z;
  const int l0 = lc * 128;
  __shared__ __align__(8) bf16 ut[130 * 16];
  const int t = threadIdx.x;
  for (int i = t; i < 130 * 4; i += 256) {
    const int lr = i >> 2, qd = i & 3;
    const int l = l0 - 2 + lr;
    uint2 val;
    val.x = 0u; val.y = 0u;
    if (l >= 0)
      val = *(const uint2*)&u[(size_t)(b * SEQLEN + l) * INNER + nh * 48 + 32 + qd * 4];
    *(uint2*)&ut[lr * 16 + qd * 4] = val;
  }
  __syncthreads();
  const size_t bn = (size_t)(b * NUM_HEADS + nh);
  for (int i = t; i < 128 * 16; i += 256) {
    const int lr = i & 127, c = i >> 7;
    const int e = nh * 48 + 32 + c;
    const float w0 = w_sf[e * 3 + 0];
    const float w1 = w_sf[e * 3 + 1];
    const float w2 = w_sf[e * 3 + 2];
    const float bb = b_sf[e];
    const float val = w0 * (float)ut[lr * 16 + c] +
                      w1 * (float)ut[(lr + 1) * 16 + c] +
                      w2 * (float)ut[(lr + 2) * 16 + c] + bb;
    vv[(bn * 16 + c) * SEQLEN + l0 + lr] = (bf16)val;
  }
}

// ---------------------------------------------------------------------------
// Causal h-weighted attention with Q/K conv fused (reads u directly).
// y[l,j] = sum_{m<=l} h[l-m]*(Q[l,:].K[m,:])*V[m,j]   -> y f32 (B,L,N*HC)
// One wave per 16-row Q tile; KV steps of 32. S -> A-layout via LDS.
// ---------------------------------------------------------------------------
__global__ __launch_bounds__(256) void attn_kernel(
    const bf16* __restrict__ u, const bf16* __restrict__ vv,
    const float* __restrict__ w_sf, const float* __restrict__ b_sf,
    const float* __restrict__ hg, float* __restrict__ y) {
  const int nh = blockIdx.x, b = blockIdx.y, qc = blockIdx.z;
  __shared__ __align__(16) float hs[SEQLEN];
  __shared__ __align__(16) bf16 st[4][16 * 40];  // stride 40: bank-conflict pad
  const int t = threadIdx.x;
  for (int i = t; i < SEQLEN / 4; i += 256)
    ((float4*)hs)[i] = ((const float4*)(hg + nh * SEQLEN))[i];
  __syncthreads();

  const int w = t >> 6, lane = t & 63;
  const int row16 = lane & 15, quad = lane >> 4;
  const int qtile = qc * 4 + w;
  const int l0 = qtile * 16;
  const bf16* ub = u + (size_t)b * SEQLEN * INNER;
  const bf16* vb = vv + (size_t)(b * NUM_HEADS + nh) * 16 * SEQLEN;

  bf16x8 zf;
#pragma unroll
  for (int j = 0; j < 8; ++j) zf[j] = (bf16)0.f;
  const f32x4 zacc = {0.f, 0.f, 0.f, 0.f};

  // per-lane conv weights (quad<2 lanes hold channels quad*8..+8)
  float wk0[8], wk1[8], wk2[8], bk[8];
  bf16x8 qf = zf;
  const int cq = nh * 48 + quad * 8;   // Q channels (quad<2)
  const int ck = cq + 16;              // K channels (quad<2)
  if (quad < 2) {
    float wq0[8], wq1[8], wq2[8], bq[8];
#pragma unroll
    for (int j = 0; j < 8; ++j) {
      wq0[j] = w_sf[(cq + j) * 3 + 0];
      wq1[j] = w_sf[(cq + j) * 3 + 1];
      wq2[j] = w_sf[(cq + j) * 3 + 2];
      bq[j] = b_sf[cq + j];
      wk0[j] = w_sf[(ck + j) * 3 + 0];
      wk1[j] = w_sf[(ck + j) * 3 + 1];
      wk2[j] = w_sf[(ck + j) * 3 + 2];
      bk[j] = b_sf[ck + j];
    }
    const int l = l0 + row16;
    bf16x8 t2 = *(const bf16x8*)&ub[(size_t)l * INNER + cq];
    bf16x8 t1 = (l >= 1) ? *(const bf16x8*)&ub[(size_t)(l - 1) * INNER + cq] : zf;
    bf16x8 t0 = (l >= 2) ? *(const bf16x8*)&ub[(size_t)(l - 2) * INNER + cq] : zf;
#pragma unroll
    for (int j = 0; j < 8; ++j)
      qf[j] = (bf16)(wq0[j] * (float)t0[j] + wq1[j] * (float)t1[j] +
                     wq2[j] * (float)t2[j] + bq[j]);
  }

  f32x4 oacc = zacc;
  bf16* sw = &st[w][0];
  const int nsteps = (qtile >> 1) + 1;
  for (int s = 0; s < nsteps; ++s) {
    const int m0 = s * 32;
    bf16x8 kf0 = zf, kf1 = zf;
    if (quad < 2) {
      {
        const int m = m0 + row16;
        bf16x8 t2 = *(const bf16x8*)&ub[(size_t)m * INNER + ck];
        bf16x8 t1 = (m >= 1) ? *(const bf16x8*)&ub[(size_t)(m - 1) * INNER + ck] : zf;
        bf16x8 t0 = (m >= 2) ? *(const bf16x8*)&ub[(size_t)(m - 2) * INNER + ck] : zf;
#pragma unroll
        for (int j = 0; j < 8; ++j)
          kf0[j] = (bf16)(wk0[j] * (float)t0[j] + wk1[j] * (float)t1[j] +
                          wk2[j] * (float)t2[j] + bk[j]);
      }
      {
        const int m = m0 + 16 + row16;  // >= 16, taps never out of range
        bf16x8 t2 = *(const bf16x8*)&ub[(size_t)m * INNER + ck];
        bf16x8 t1 = *(const bf16x8*)&ub[(size_t)(m - 1) * INNER + ck];
        bf16x8 t0 = *(const bf16x8*)&ub[(size_t)(m - 2) * INNER + ck];
#pragma unroll
        for (int j = 0; j < 8; ++j)
          kf1[j] = (bf16)(wk0[j] * (float)t0[j] + wk1[j] * (float)t1[j] +
                          wk2[j] * (float)t2[j] + bk[j]);
      }
    }
    f32x4 s0 = __builtin_amdgcn_mfma_f32_16x16x32_bf16(qf, kf0, zacc, 0, 0, 0);
    f32x4 s1 = __builtin_amdgcn_mfma_f32_16x16x32_bf16(qf, kf1, zacc, 0, 0, 0);

    // S element (r, lane): row l = l0+quad*4+r, col m = m0(+16)+row16
#pragma unroll
    for (int r = 0; r < 4; ++r) {
      const int l = l0 + quad * 4 + r;
      {
        const int m = m0 + row16;
        const float f = (m <= l) ? s0[r] * hs[l - m] : 0.f;
        sw[(quad * 4 + r) * 40 + row16] = (bf16)f;
      }
      {
        const int m = m0 + 16 + row16;
        const float f = (m <= l) ? s1[r] * hs[l - m] : 0.f;
        sw[(quad * 4 + r) * 40 + 16 + row16] = (bf16)f;
      }
    }
    // keep stores before re-read and drain the DS queue (wave-local reuse)
    asm volatile("s_waitcnt lgkmcnt(0)" ::: "memory");
    // read back in A-layout: row l = row16, k(m) = quad*8+j (wave-local LDS)
    const bf16x8 sf = *(const bf16x8*)&sw[row16 * 40 + quad * 8];
    // V B-frag: n(j) = row16, k(m) = quad*8+j ; V is (HC, L) channel-major
    const bf16x8 vf = *(const bf16x8*)&vb[row16 * SEQLEN + m0 + quad * 8];
    oacc = __builtin_amdgcn_mfma_f32_16x16x32_bf16(sf, vf, oacc, 0, 0, 0);
    asm volatile("" ::: "memory");  // keep the re-read before next-iter stores
  }

  // y layout (B, L, N*HC): d = nh*16 + j  (f32)
#pragma unroll
  for (int r = 0; r < 4; ++r) {
    const int l = l0 + quad * 4 + r;
    y[((size_t)(b * SEQLEN + l) * NUM_HEADS + nh) * 16 + row16] = oacc[r];
  }
}

// ---------------------------------------------------------------------------
// RMSNorm over D=768 per row: y f32 in, yn bf16 out, * norm_w (f32)
// ---------------------------------------------------------------------------
__global__ __launch_bounds__(256) void rmsnorm_k(
    const float* __restrict__ y, const float* __restrict__ nw,
    bf16* __restrict__ yn) {
  const int row = blockIdx.x;
  const int t = threadIdx.x;
  const float* yr = y + (size_t)row * D_MODEL;
  const float v0 = yr[t];
  const float v1 = yr[t + 256];
  const float v2 = yr[t + 512];
  float ss = v0 * v0 + v1 * v1 + v2 * v2;
#pragma unroll
  for (int off = 32; off >= 1; off >>= 1) ss += __shfl_down(ss, off, 64);
  __shared__ float red[4];
  if ((t & 63) == 0) red[t >> 6] = ss;
  __syncthreads();
  const float tot = red[0] + red[1] + red[2] + red[3];
  const float r = rsqrtf(tot * (1.f / 768.f) + EPSF);
  bf16* yo = yn + (size_t)row * D_MODEL;
  yo[t] = (bf16)(v0 * r * nw[t]);
  yo[t + 256] = (bf16)(v1 * r * nw[t + 256]);
  yo[t + 512] = (bf16)(v2 * r * nw[t + 512]);
}

// ---------------------------------------------------------------------------
extern "C" void kernel_launch(void* const* d_in, const int* in_sizes, int n_in,
                              void* d_out, int out_size, void* d_ws,
                              size_t ws_size, hipStream_t stream) {
  const float* inputs = (const float*)d_in[0];
  const float* w_in = (const float*)d_in[1];
  const float* b_in = (const float*)d_in[2];
  const float* w_sf = (const float*)d_in[3];
  const float* b_sf = (const float*)d_in[4];
  const float* hb = (const float*)d_in[5];
  const float* norm_w = (const float*)d_in[6];
  const float* w_out = (const float*)d_in[7];
  const float* b_out = (const float*)d_in[8];

  // ws plan (~36 MB):
  //   u        18.9 MB bf16 (M_ROWS x INNER)
  //   v         6.3 MB bf16
  //   in_bf16   6.3 MB bf16 (dead after GEMM1; reused as yn)
  //   w_in_b16  3.5 MB bf16
  //   w_out_b16 1.2 MB bf16
  // y (f32) lives in d_out (dead after rmsnorm, overwritten by GEMM2).
  char* ws = (char*)d_ws;
  const size_t U_B = (size_t)M_ROWS * INNER * 2;
  const size_t V_B = (size_t)BATCH * NUM_HEADS * HEAD_CH * SEQLEN * 2;
  const size_t INB_B = (size_t)M_ROWS * D_MODEL * 2;
  const size_t WIN_B = (size_t)INNER * D_MODEL * 2;
  bf16* u = (bf16*)(ws);
  bf16* v = (bf16*)(ws + U_B);
  bf16* in16 = (bf16*)(ws + U_B + V_B);
  bf16* win16 = (bf16*)(ws + U_B + V_B + INB_B);
  bf16* wout16 = (bf16*)(ws + U_B + V_B + INB_B + WIN_B);
  bf16* yn = in16;  // in16 dead after GEMM1
  float* y = (float*)d_out;
  float* out = (float*)d_out;

  const int n4_in = M_ROWS * D_MODEL / 4;
  const int n4_win = INNER * D_MODEL / 4;
  const int n4_wout = D_MODEL * D_MODEL / 4;
  hipLaunchKernelGGL(cvt_f32_bf16, dim3((n4_in + 255) / 256), dim3(256), 0,
                     stream, inputs, in16, n4_in);
  hipLaunchKernelGGL(cvt_f32_bf16, dim3((n4_win + 255) / 256), dim3(256), 0,
                     stream, w_in, win16, n4_win);
  hipLaunchKernelGGL(cvt_f32_bf16, dim3((n4_wout + 255) / 256), dim3(256), 0,
                     stream, w_out, wout16, n4_wout);

  hipLaunchKernelGGL((gemm_bt<INNER, false, bf16>), dim3(32, 18), dim3(256), 0,
                     stream, in16, win16, b_in, (const float*)nullptr, u, 768);
  hipLaunchKernelGGL(conv_v, dim3(48, 2, 16), dim3(256), 0, stream, u, w_sf,
                     b_sf, v);
  hipLaunchKernelGGL(attn_kernel, dim3(48, 2, 32), dim3(256), 0, stream, u, v,
                     w_sf, b_sf, hb, y);
  hipLaunchKernelGGL(rmsnorm_k, dim3(M_ROWS), dim3(256), 0, stream, y, norm_w,
                     yn);
  hipLaunchKernelGGL((gemm_bt<D_MODEL, true, float>), dim3(32, 6), dim3(256),
                     0, stream, yn, wout16, b_out, inputs, out, 768);
}

// Round 4
// 222.099 us; speedup vs baseline: 1.8483x; 1.8483x over previous
//
#include <hip/hip_runtime.h>
#include <hip/hip_bf16.h>
#include <stdint.h>

typedef __bf16 bf16;
typedef __bf16 bf16x4 __attribute__((ext_vector_type(4)));
typedef __bf16 bf16x8 __attribute__((ext_vector_type(8)));
typedef float f32x4 __attribute__((ext_vector_type(4)));
typedef float f32x16 __attribute__((ext_vector_type(16)));

#define D_MODEL 768
#define NUM_HEADS 48
#define HEAD_CH 16
#define INNER 2304
#define BATCH 2
#define SEQLEN 2048
#define M_ROWS (BATCH * SEQLEN)
#define EPSF 1e-6f

// async global->LDS, 16B per lane. LDS dest must be wave-uniform base + lane*16.
__device__ inline void gload_lds16(const void* g, void* l) {
  __builtin_amdgcn_global_load_lds((__attribute__((address_space(1))) void*)(g),
                                   (__attribute__((address_space(3))) void*)(l),
                                   16, 0, 0);
}

// ---------------------------------------------------------------------------
// f32 -> bf16 convert (memory-bound, float4 in / bf16x4 out)
// ---------------------------------------------------------------------------
__global__ __launch_bounds__(256) void cvt_f32_bf16(
    const float* __restrict__ src, bf16* __restrict__ dst, int n4) {
  const int i = blockIdx.x * 256 + threadIdx.x;
  if (i < n4) {
    const float4 v = ((const float4*)src)[i];
    bf16x4 o;
    o[0] = (bf16)v.x; o[1] = (bf16)v.y; o[2] = (bf16)v.z; o[3] = (bf16)v.w;
    ((bf16x4*)dst)[i] = o;
  }
}

// ---------------------------------------------------------------------------
// GEMM: C[m,n] = sum_k A[m,k]*W[n,k] + bias[n] (+ skip[m,n]); A (M,K), W (N,K)
// m97 pattern: 128x128 tile, BK=32, 4 waves each 64x64, global_load_lds x16.
// ---------------------------------------------------------------------------
template <int NCOLS, bool ADD_SKIP, typename CT>
__global__ __launch_bounds__(256) void gemm_bt(
    const bf16* __restrict__ A, const bf16* __restrict__ W,
    const float* __restrict__ bias, const float* __restrict__ skip,
    CT* __restrict__ C, int K) {
  __shared__ __align__(16) bf16 As[128 * 32];
  __shared__ __align__(16) bf16 Bs[128 * 32];
  const int t = threadIdx.x;
  const int lane = t & 63, w = t >> 6;
  const int wm = (w >> 1) * 64, wn = (w & 1) * 64;
  const int row16 = lane & 15, quad = lane >> 4;
  const int m0 = blockIdx.x * 128, n0 = blockIdx.y * 128;

  f32x4 zero4 = {0.f, 0.f, 0.f, 0.f};
  f32x4 acc[4][4];
#pragma unroll
  for (int mi = 0; mi < 4; ++mi)
#pragma unroll
    for (int ni = 0; ni < 4; ++ni) acc[mi][ni] = zero4;

  const int arow = t >> 2;
  const int acol = (t & 3) * 8;
  const bf16* Ab = A + (size_t)m0 * K;
  const bf16* Wb = W + (size_t)n0 * K;

  for (int kt = 0; kt < K; kt += 32) {
    gload_lds16(Ab + (size_t)arow * K + kt + acol, As + t * 8);
    gload_lds16(Ab + (size_t)(64 + arow) * K + kt + acol, As + 2048 + t * 8);
    gload_lds16(Wb + (size_t)arow * K + kt + acol, Bs + t * 8);
    gload_lds16(Wb + (size_t)(64 + arow) * K + kt + acol, Bs + 2048 + t * 8);
    __syncthreads();

    bf16x8 af[4], wf[4];
#pragma unroll
    for (int mi = 0; mi < 4; ++mi)
      af[mi] = *(const bf16x8*)&As[(wm + mi * 16 + row16) * 32 + quad * 8];
#pragma unroll
    for (int ni = 0; ni < 4; ++ni)
      wf[ni] = *(const bf16x8*)&Bs[(wn + ni * 16 + row16) * 32 + quad * 8];
#pragma unroll
    for (int mi = 0; mi < 4; ++mi)
#pragma unroll
      for (int ni = 0; ni < 4; ++ni)
        acc[mi][ni] = __builtin_amdgcn_mfma_f32_16x16x32_bf16(
            af[mi], wf[ni], acc[mi][ni], 0, 0, 0);
    __syncthreads();
  }

#pragma unroll
  for (int mi = 0; mi < 4; ++mi) {
#pragma unroll
    for (int ni = 0; ni < 4; ++ni) {
      const int col = n0 + wn + ni * 16 + row16;
      const float bv = bias[col];
#pragma unroll
      for (int r = 0; r < 4; ++r) {
        const int row = m0 + wm + mi * 16 + quad * 4 + r;
        float v = acc[mi][ni][r] + bv;
        if (ADD_SKIP) v += skip[(size_t)row * NCOLS + col];
        C[(size_t)row * NCOLS + col] = (CT)v;
      }
    }
  }
}

// ---------------------------------------------------------------------------
// K+V causal width-3 conv: head ch 16..31 -> K (B,N,L,16); 32..47 -> V (B,N,16,L)
// ---------------------------------------------------------------------------
__global__ __launch_bounds__(256) void conv_kv(
    const bf16* __restrict__ u, const float* __restrict__ w_sf,
    const float* __restrict__ b_sf, bf16* __restrict__ kk,
    bf16* __restrict__ vv) {
  const int nh = blockIdx.x, b = blockIdx.y, lc = blockIdx.z;
  const int l0 = lc * 128;
  __shared__ __align__(8) bf16 ut[130 * 32];
  const int t = threadIdx.x;
  for (int i = t; i < 130 * 8; i += 256) {
    const int lr = i >> 3, qd = i & 7;
    const int l = l0 - 2 + lr;
    uint2 val;
    val.x = 0u; val.y = 0u;
    if (l >= 0)
      val = *(const uint2*)&u[(size_t)(b * SEQLEN + l) * INNER + nh * 48 + 16 + qd * 4];
    *(uint2*)&ut[lr * 32 + qd * 4] = val;
  }
  __syncthreads();
  const size_t bn = (size_t)(b * NUM_HEADS + nh);
  // K: head channels 16..31 (tile cols 0..15)
  for (int i = t; i < 128 * 16; i += 256) {
    const int c = i & 15, lr = i >> 4;
    const int e = nh * 48 + 16 + c;
    const float val = w_sf[e * 3 + 0] * (float)ut[lr * 32 + c] +
                      w_sf[e * 3 + 1] * (float)ut[(lr + 1) * 32 + c] +
                      w_sf[e * 3 + 2] * (float)ut[(lr + 2) * 32 + c] + b_sf[e];
    kk[(bn * SEQLEN + l0 + lr) * 16 + c] = (bf16)val;
  }
  // V: head channels 32..47 (tile cols 16..31)
  for (int i = t; i < 128 * 16; i += 256) {
    const int lr = i & 127, c = i >> 7;
    const int e = nh * 48 + 32 + c;
    const float val = w_sf[e * 3 + 0] * (float)ut[lr * 32 + 16 + c] +
                      w_sf[e * 3 + 1] * (float)ut[(lr + 1) * 32 + 16 + c] +
                      w_sf[e * 3 + 2] * (float)ut[(lr + 2) * 32 + 16 + c] + b_sf[e];
    vv[(bn * 16 + c) * SEQLEN + l0 + lr] = (bf16)val;
  }
}

// ---------------------------------------------------------------------------
// Causal h-weighted attention, 32-row Q tile per wave, 4-way KV split/block.
// S^T = mfma_32x32x16(Kfrag, Qfrag); h-weight via zero-padded hx table;
// PV = 2 x mfma_16x16x32. Q-conv fused (once per wave). Barrier-free K-loop.
// ---------------------------------------------------------------------------
__global__ __launch_bounds__(256) void attn_kernel(
    const bf16* __restrict__ u, const bf16* __restrict__ kk,
    const bf16* __restrict__ vv, const float* __restrict__ w_sf,
    const float* __restrict__ b_sf, const float* __restrict__ hg,
    float* __restrict__ y) {
  const int nh = blockIdx.x, b = blockIdx.y, q32 = blockIdx.z;
  const int l0 = q32 * 32;
  __shared__ __align__(16) float hx[32 + SEQLEN];   // hx[32+d] = h[d], 0 for d<0
  __shared__ __align__(16) bf16 st[4 * 32 * 40];    // per-wave 32x40 S-tile
  const int t = threadIdx.x;
  for (int i = t; i < 32 + SEQLEN; i += 256)
    hx[i] = (i >= 32) ? hg[nh * SEQLEN + i - 32] : 0.f;
  __syncthreads();

  const int w = t >> 6, lane = t & 63;
  const int l31 = lane & 31, hi = lane >> 5;
  const int row16 = lane & 15, quad = lane >> 4;
  const bf16* ub = u + (size_t)b * SEQLEN * INNER;
  const size_t bn = (size_t)(b * NUM_HEADS + nh);
  const bf16* kb = kk + bn * SEQLEN * 16;
  const bf16* vb = vv + bn * 16 * SEQLEN;

  bf16x8 zf;
#pragma unroll
  for (int j = 0; j < 8; ++j) zf[j] = (bf16)0.f;
  const f32x4 zacc4 = {0.f, 0.f, 0.f, 0.f};
  f32x16 zacc16;
#pragma unroll
  for (int j = 0; j < 16; ++j) zacc16[j] = 0.f;

  // ---- fused Q conv: Q[l0+l31][ch hi*8..+8], once per wave ----
  bf16x8 qf;
  {
    const int cq = nh * 48 + hi * 8;
    const int l = l0 + l31;
    bf16x8 t2 = *(const bf16x8*)&ub[(size_t)l * INNER + cq];
    bf16x8 t1 = (l >= 1) ? *(const bf16x8*)&ub[(size_t)(l - 1) * INNER + cq] : zf;
    bf16x8 t0 = (l >= 2) ? *(const bf16x8*)&ub[(size_t)(l - 2) * INNER + cq] : zf;
#pragma unroll
    for (int j = 0; j < 8; ++j)
      qf[j] = (bf16)(w_sf[(cq + j) * 3 + 0] * (float)t0[j] +
                     w_sf[(cq + j) * 3 + 1] * (float)t1[j] +
                     w_sf[(cq + j) * 3 + 2] * (float)t2[j] + b_sf[cq + j]);
  }

  bf16* sw = &st[w * 32 * 40];
  f32x4 o0 = zacc4, o1 = zacc4;

  int mc = w * 32;
  bf16x8 kf = zf, vf = zf;
  if (mc <= l0) {
    kf = *(const bf16x8*)&kb[(mc + l31) * 16 + hi * 8];
    vf = *(const bf16x8*)&vb[row16 * SEQLEN + mc + quad * 8];
  }
  for (; mc <= l0; mc += 128) {
    const int mn = mc + 128;
    bf16x8 kf2 = zf, vf2 = zf;
    if (mn <= l0) {  // prefetch next chunk
      kf2 = *(const bf16x8*)&kb[(mn + l31) * 16 + hi * 8];
      vf2 = *(const bf16x8*)&vb[row16 * SEQLEN + mn + quad * 8];
    }
    // S^T[m=row][l=col] = sum_ch K*Q
    f32x16 s = __builtin_amdgcn_mfma_f32_32x32x16_bf16(kf, qf, zacc16, 0, 0, 0);

    // h-weight + causal mask (hx zero pad), pack 4 rows -> b64 LDS store
    const int hb0 = 32 + (l0 - mc) + l31 - 4 * hi;  // minus 8g per group
#pragma unroll
    for (int g = 0; g < 4; ++g) {
      const float* hp = &hx[hb0 - 8 * g - 3];  // hp[3-rr] = hx for row rr
      bf16x4 pk;
      pk[0] = (bf16)(s[4 * g + 0] * hp[3]);
      pk[1] = (bf16)(s[4 * g + 1] * hp[2]);
      pk[2] = (bf16)(s[4 * g + 2] * hp[1]);
      pk[3] = (bf16)(s[4 * g + 3] * hp[0]);
      *(bf16x4*)&sw[l31 * 40 + 8 * g + 4 * hi] = pk;
    }
    asm volatile("s_waitcnt lgkmcnt(0)" ::: "memory");  // stores before reads
    // PV: A = S[l][m] (b128), B = V[m][j] frag (shared by both halves)
    const bf16x8 sf0 = *(const bf16x8*)&sw[row16 * 40 + quad * 8];
    const bf16x8 sf1 = *(const bf16x8*)&sw[(row16 + 16) * 40 + quad * 8];
    o0 = __builtin_amdgcn_mfma_f32_16x16x32_bf16(sf0, vf, o0, 0, 0, 0);
    o1 = __builtin_amdgcn_mfma_f32_16x16x32_bf16(sf1, vf, o1, 0, 0, 0);
    asm volatile("" ::: "memory");  // reads before next-iter stores
    kf = kf2; vf = vf2;
  }

  // per-wave O into own LDS region (f32 32x16), then block reduce
  float* ob = (float*)&st[w * 32 * 40];
#pragma unroll
  for (int r = 0; r < 4; ++r) {
    ob[(quad * 4 + r) * 16 + row16] = o0[r];
    ob[(quad * 4 + r + 16) * 16 + row16] = o1[r];
  }
  __syncthreads();
  for (int i = t; i < 32 * 16; i += 256) {
    const int l = i >> 4, j = i & 15;
    float sum = 0.f;
#pragma unroll
    for (int ww = 0; ww < 4; ++ww)
      sum += ((const float*)&st[ww * 32 * 40])[l * 16 + j];
    y[((size_t)(b * SEQLEN + l0 + l) * NUM_HEADS + nh) * 16 + j] = sum;
  }
}

// ---------------------------------------------------------------------------
// RMSNorm over D=768 per row: y f32 in, yn bf16 out, * norm_w (f32)
// ---------------------------------------------------------------------------
__global__ __launch_bounds__(256) void rmsnorm_k(
    const float* __restrict__ y, const float* __restrict__ nw,
    bf16* __restrict__ yn) {
  const int row = blockIdx.x;
  const int t = threadIdx.x;
  const float* yr = y + (size_t)row * D_MODEL;
  const float v0 = yr[t];
  const float v1 = yr[t + 256];
  const float v2 = yr[t + 512];
  float ss = v0 * v0 + v1 * v1 + v2 * v2;
#pragma unroll
  for (int off = 32; off >= 1; off >>= 1) ss += __shfl_down(ss, off, 64);
  __shared__ float red[4];
  if ((t & 63) == 0) red[t >> 6] = ss;
  __syncthreads();
  const float tot = red[0] + red[1] + red[2] + red[3];
  const float r = rsqrtf(tot * (1.f / 768.f) + EPSF);
  bf16* yo = yn + (size_t)row * D_MODEL;
  yo[t] = (bf16)(v0 * r * nw[t]);
  yo[t + 256] = (bf16)(v1 * r * nw[t + 256]);
  yo[t + 512] = (bf16)(v2 * r * nw[t + 512]);
}

// ---------------------------------------------------------------------------
extern "C" void kernel_launch(void* const* d_in, const int* in_sizes, int n_in,
                              void* d_out, int out_size, void* d_ws,
                              size_t ws_size, hipStream_t stream) {
  const float* inputs = (const float*)d_in[0];
  const float* w_in = (const float*)d_in[1];
  const float* b_in = (const float*)d_in[2];
  const float* w_sf = (const float*)d_in[3];
  const float* b_sf = (const float*)d_in[4];
  const float* hb = (const float*)d_in[5];
  const float* norm_w = (const float*)d_in[6];
  const float* w_out = (const float*)d_in[7];
  const float* b_out = (const float*)d_in[8];

  // ws plan (~36.2 MB, proven size from round 3):
  //   u      18.9 MB bf16   (alive through attn: Q-conv reads it)
  //   v       6.3 MB bf16
  //   slot    6.3 MB bf16   (in16 for GEMM1 -> k for attn -> yn for GEMM2)
  //   win16   3.5 MB bf16
  //   wout16  1.2 MB bf16
  // y (f32) lives in d_out (dead after rmsnorm, overwritten by GEMM2).
  char* ws = (char*)d_ws;
  const size_t U_B = (size_t)M_ROWS * INNER * 2;
  const size_t V_B = (size_t)BATCH * NUM_HEADS * HEAD_CH * SEQLEN * 2;
  const size_t SLOT_B = (size_t)M_ROWS * D_MODEL * 2;
  const size_t WIN_B = (size_t)INNER * D_MODEL * 2;
  bf16* u = (bf16*)(ws);
  bf16* v = (bf16*)(ws + U_B);
  bf16* in16 = (bf16*)(ws + U_B + V_B);
  bf16* k16 = in16;  // in16 dead after GEMM1
  bf16* yn = in16;   // k dead after attn
  bf16* win16 = (bf16*)(ws + U_B + V_B + SLOT_B);
  bf16* wout16 = (bf16*)(ws + U_B + V_B + SLOT_B + WIN_B);
  float* y = (float*)d_out;
  float* out = (float*)d_out;

  const int n4_in = M_ROWS * D_MODEL / 4;
  const int n4_win = INNER * D_MODEL / 4;
  const int n4_wout = D_MODEL * D_MODEL / 4;
  hipLaunchKernelGGL(cvt_f32_bf16, dim3((n4_in + 255) / 256), dim3(256), 0,
                     stream, inputs, in16, n4_in);
  hipLaunchKernelGGL(cvt_f32_bf16, dim3((n4_win + 255) / 256), dim3(256), 0,
                     stream, w_in, win16, n4_win);
  hipLaunchKernelGGL(cvt_f32_bf16, dim3((n4_wout + 255) / 256), dim3(256), 0,
                     stream, w_out, wout16, n4_wout);

  hipLaunchKernelGGL((gemm_bt<INNER, false, bf16>), dim3(32, 18), dim3(256), 0,
                     stream, in16, win16, b_in, (const float*)nullptr, u, 768);
  hipLaunchKernelGGL(conv_kv, dim3(48, 2, 16), dim3(256), 0, stream, u, w_sf,
                     b_sf, k16, v);
  hipLaunchKernelGGL(attn_kernel, dim3(48, 2, 64), dim3(256), 0, stream, u,
                     k16, v, w_sf, b_sf, hb, y);
  hipLaunchKernelGGL(rmsnorm_k, dim3(M_ROWS), dim3(256), 0, stream, y, norm_w,
                     yn);
  hipLaunchKernelGGL((gemm_bt<D_MODEL, true, float>), dim3(32, 6), dim3(256),
                     0, stream, yn, wout16, b_out, inputs, out, 768);
}